// Round 3
// baseline (218.370 us; speedup 1.0000x reference)
//
#include <hip/hip_runtime.h>

#define BATCH 128
#define NPTS  4096
#define LPT   8                  // cells per lane
#define CHUNK 512                // cells per wave (64 lanes x 8)
#define WPR   14                 // waves per row
#define HALO  112                // > 99 steps of edge contamination

// Halved-coefficient flux: g(u) = 0.5*f(u), ah(u) = 0.5*|f'(u)|
// f  = 1.5u + 0.75b u^2 + (-0.5-2b) u^3 + 1.5b u^4 - 0.25b u^6,  b = beta/12
// f' = 1.5 + 1.5b u - (1.5+6b) u^2 + 6b u^3 - 1.5b u^5
__device__ __forceinline__ void flux_eval(float u, float& g, float& ah) {
    constexpr float b  = 0.1f / 12.0f;
    constexpr float c6 = 0.5f * (-0.25f * b);
    constexpr float c4 = 0.5f * ( 1.5f  * b);
    constexpr float c3 = 0.5f * (-0.5f - 2.0f * b);
    constexpr float c2 = 0.5f * ( 0.75f * b);
    constexpr float c1 = 0.5f * ( 1.5f);
    constexpr float d5 = 0.5f * (-1.5f * b);
    constexpr float d3 = 0.5f * ( 6.0f * b);
    constexpr float d2 = 0.5f * (-(1.5f + 6.0f * b));
    constexpr float d1 = 0.5f * ( 1.5f * b);
    constexpr float d0 = 0.5f * ( 1.5f);

    float t = c6 * u;            // Horner, c5 == 0: ends as 0.5*f(u)/u
    t = fmaf(t, u, c4);
    t = fmaf(t, u, c3);
    t = fmaf(t, u, c2);
    t = fmaf(t, u, c1);
    g = u * t;

    float e = d5 * u;            // Horner, d4 == 0: d5u^5+d3u^3+d2u^2+d1u+d0
    e = fmaf(e, u, d3);
    e = fmaf(e, u, d2);
    e = fmaf(e, u, d1);
    e = fmaf(e, u, d0);
    ah = fabsf(e);
}

// One wave per 512-cell chunk. No LDS, no barriers — neighbor exchange via
// wave shuffles; chunk overlap (halo 112) absorbs 99 steps of contamination.
// Owned regions tile [0,4096) exactly:
//   w=0:    start 0,    owns local [0,400)
//   w=1..12 start 288w, owns local [112,400)
//   w=13:   start 3584, owns local [272,512)
__global__ __launch_bounds__(64) void pde_wave_autonomous(
        const float* __restrict__ init,
        const int*   __restrict__ stepnum_p,
        float*       __restrict__ out) {
    const int bx   = blockIdx.x;
    const int row  = bx / WPR;
    const int w    = bx - row * WPR;
    const int lane = threadIdx.x;            // 0..63

    const int start = (w == 0) ? 0 : ((w == WPR - 1) ? (NPTS - CHUNK) : 288 * w);
    const int ownLo = (w == 0) ? 0 : ((w == WPR - 1) ? 272 : HALO);
    const int ownHi = (w == WPR - 1) ? CHUNK : 400;
    const int lc    = lane * LPT;            // local first cell of this lane

    const bool dostore = (lc >= ownLo) && (lc + LPT <= ownHi);
    const bool rowL    = (w == 0)       && (lane == 0);
    const bool rowR    = (w == WPR - 1) && (lane == 63);
    const int  stepnum = *stepnum_p;

    const size_t rowoff = (size_t)row * NPTS + (size_t)(start + lc);

    float v[LPT];
    {
        const float4 a = *(const float4*)(init + rowoff);
        const float4 c = *(const float4*)(init + rowoff + 4);
        v[0]=a.x; v[1]=a.y; v[2]=a.z; v[3]=a.w;
        v[4]=c.x; v[5]=c.y; v[6]=c.z; v[7]=c.w;
    }
    if (dostore) {                            // out[step 0] = init (no BC at s=0)
        *(float4*)(out + rowoff)     = make_float4(v[0],v[1],v[2],v[3]);
        *(float4*)(out + rowoff + 4) = make_float4(v[4],v[5],v[6],v[7]);
    }

    for (int s = 1; s < stepnum; ++s) {
        float g[LPT], a[LPT];
#pragma unroll
        for (int k = 0; k < LPT; ++k) flux_eval(v[k], g[k], a[k]);

        // lane-boundary exchange (shuffle = ds_bpermute; lane 0/63 clamp garbage
        // only feeds halo or boundary-copied cells)
        const float vl = __shfl_up (v[LPT-1], 1, 64);
        const float gl = __shfl_up (g[LPT-1], 1, 64);
        const float al = __shfl_up (a[LPT-1], 1, 64);
        const float vr = __shfl_down(v[0], 1, 64);
        const float gr = __shfl_down(g[0], 1, 64);
        const float ar = __shfl_down(a[0], 1, 64);

        float fh[LPT + 1];                    // fh == reference f_half (0.5 folded)
        fh[0] = gl + g[0] - fmaxf(al, a[0]) * (v[0] - vl);
#pragma unroll
        for (int m = 1; m < LPT; ++m)
            fh[m] = g[m-1] + g[m] - fmaxf(a[m-1], a[m]) * (v[m] - v[m-1]);
        fh[LPT] = g[LPT-1] + gr - fmaxf(a[LPT-1], ar) * (vr - v[LPT-1]);

        float nu[LPT];
#pragma unroll
        for (int k = 0; k < LPT; ++k)
            nu[k] = fmaf(-0.5f, fh[k+1] - fh[k], v[k]);   // r = DT/DX = 0.5 exact
        if (rowL) nu[0] = nu[1];              // u_new[0]   = u_new[1]
        if (rowR) nu[7] = nu[6];              // u_new[N-1] = u_new[N-2]
#pragma unroll
        for (int k = 0; k < LPT; ++k) v[k] = nu[k];

        if (dostore) {                        // fire-and-forget; nothing reads it
            float* o = out + (size_t)s * ((size_t)BATCH * NPTS) + rowoff;
            *(float4*)o       = make_float4(v[0],v[1],v[2],v[3]);
            *(float4*)(o + 4) = make_float4(v[4],v[5],v[6],v[7]);
        }
    }
}

extern "C" void kernel_launch(void* const* d_in, const int* in_sizes, int n_in,
                              void* d_out, int out_size, void* d_ws, size_t ws_size,
                              hipStream_t stream) {
    const float* init  = (const float*)d_in[0];
    const int*   steps = (const int*)d_in[1];
    float*       out   = (float*)d_out;
    pde_wave_autonomous<<<BATCH * WPR, 64, 0, stream>>>(init, steps, out);
}